// Round 8
// baseline (672.951 us; speedup 1.0000x reference)
//
#include <hip/hip_runtime.h>
#include <hip/hip_bf16.h>
#include <cstddef>
#include <cstdint>

#define BB   32
#define TT   2048
#define DIN  512
#define DD   512
#define NN   3072
#define PW   3072    // proj row width (f16): col = p*1024 + d*2 + q, gate k=2p+q
#define PF   16      // scan prefetch depth (steps)

#define BMT 256      // GEMM tile M
#define BNT 256      // GEMM tile N
#define BKT 64       // GEMM K-tile
#define NKT (DIN / BKT)   // 8 K-tiles

typedef __attribute__((ext_vector_type(4))) float f32x4;
typedef __attribute__((ext_vector_type(8))) short s16x8;

// ---------------------------------------------------------------------------
// helpers
// ---------------------------------------------------------------------------
__device__ __forceinline__ void gl2lds16(const void* g, void* l) {
    __builtin_amdgcn_global_load_lds(
        (const __attribute__((address_space(1))) unsigned*)g,
        (__attribute__((address_space(3))) unsigned*)l, 16, 0, 0);
}

__device__ __forceinline__ unsigned short bfr(float f) {   // f32 -> bf16 RNE
    unsigned u = __float_as_uint(f);
    u += 0x7fffu + ((u >> 16) & 1u);
    return (unsigned short)(u >> 16);
}

__device__ __forceinline__ float ftanh(float x) {
    return 1.f - 2.f * __builtin_amdgcn_rcpf(1.f + __builtin_amdgcn_exp2f(x * 2.885390082f));
}

__device__ __forceinline__ float h2lo(unsigned u) {
    return (float)__builtin_bit_cast(_Float16, (unsigned short)(u & 0xffffu));
}
__device__ __forceinline__ float h2hi(unsigned u) {
    return (float)__builtin_bit_cast(_Float16, (unsigned short)(u >> 16));
}

// ---------------------------------------------------------------------------
// convert x [B][T][DIN] f32 -> x3 fragment-tiled bf16:
//   row r = t*32+b, rblk = r>>4, lr = r&15, kblk = k>>3, e = k&7
//   x3[((rblk*64 + kblk)*16 + lr)*8 + e]
// A wave's MFMA fragment load (16 rows x 8 k) is then 1 KB contiguous.
// One thread per 8 k (one full 16B granule).
// ---------------------------------------------------------------------------
__global__ __launch_bounds__(256) void convert_x(
    const float* __restrict__ x, unsigned short* __restrict__ x3)
{
    const int total8 = BB * TT * DIN / 8;
    for (int idx = blockIdx.x * 256 + threadIdx.x; idx < total8;
         idx += gridDim.x * 256) {
        int e = idx * 8;
        int b = e >> 20;            // /(T*DIN)
        int t = (e >> 9) & 2047;    // /DIN % T
        int i = e & 511;            // %DIN (multiple of 8)
        float4 v0 = *(const float4*)(x + (size_t)e);
        float4 v1 = *(const float4*)(x + (size_t)e + 4);
        int r    = (t << 5) | b;
        int rblk = r >> 4, lr = r & 15;
        int kblk = i >> 3;
        unsigned short o[8];
        o[0] = bfr(v0.x); o[1] = bfr(v0.y); o[2] = bfr(v0.z); o[3] = bfr(v0.w);
        o[4] = bfr(v1.x); o[5] = bfr(v1.y); o[6] = bfr(v1.z); o[7] = bfr(v1.w);
        *(uint4*)(x3 + (size_t)rblk * 8192 + kblk * 128 + lr * 8) =
            *(const uint4*)o;
    }
}

// ---------------------------------------------------------------------------
// convert W: W2 row c (pair-planar): p = c>>10, d = (c&1023)>>1, q = c&1,
// gate k = 2p+q, original W row o = k*512 + d. bias permuted likewise.
// ---------------------------------------------------------------------------
__global__ __launch_bounds__(128) void convert_w(
    const float* __restrict__ W, const float* __restrict__ bias,
    unsigned short* __restrict__ W2, float* __restrict__ bias2)
{
    int c = blockIdx.x;            // 0..3071
    int p = c >> 10, d = (c & 1023) >> 1, q = c & 1;
    int o = ((2 * p + q) << 9) + d;
    const float* src = W + (size_t)o * DIN;
    unsigned short* dst = W2 + (size_t)c * DIN;
    int i = threadIdx.x * 4;
    float4 v = *(const float4*)(src + i);
    ushort4 u;
    u.x = bfr(v.x); u.y = bfr(v.y); u.z = bfr(v.z); u.w = bfr(v.w);
    *(ushort4*)(dst + i) = u;
    if (threadIdx.x == 0) bias2[c] = bias[o];
}

// ---------------------------------------------------------------------------
// 256x256 8-wave MFMA GEMM, A streamed DIRECTLY from global (tiled x3, fully
// coalesced per-wave 1KB loads, no barrier coupling), B (W2, L2-resident) via
// dbuf LDS (64 KB, T2 swizzle), 2 barriers + counted vmcnt(4) per K-tile.
// Operands swapped (A-op = W2 frag) -> packed 8B ushort4 epilogue stores.
// ---------------------------------------------------------------------------
__global__ __launch_bounds__(512, 2) void gemm_proj9(
    const unsigned short* __restrict__ x3,    // fragment-tiled
    const unsigned short* __restrict__ W2,    // [3072][512] bf16 (permuted)
    const float* __restrict__ bias2,          // [3072] (permuted)
    _Float16* __restrict__ proj,              // [Mc][PW]
    int t0)
{
    __shared__ unsigned short Bs[2][256 * 64];   // 64 KB dbuf

    // XCD-bijective swizzle (m204): contiguous work per XCD
    const unsigned nwg = gridDim.x;
    const unsigned fb  = blockIdx.x;
    const unsigned qq  = nwg >> 3, rr8 = nwg & 7;
    const unsigned xcd = fb & 7, sid = fb >> 3;
    const unsigned work = (xcd < rr8 ? xcd * (qq + 1)
                                     : rr8 * (qq + 1) + (xcd - rr8) * qq) + sid;
    const int bx = (int)(work % (NN / BNT));    // 12 col tiles
    const int by = (int)(work / (NN / BNT));

    const int tid  = threadIdx.x;
    const int row0 = by * BMT;                  // chunk-local
    const int col0 = bx * BNT;

    const int lane = tid & 63;
    const int wv   = tid >> 6;       // 0..7
    const int wm   = wv >> 2;        // 0..1  (M half)
    const int wn   = wv & 3;         // 0..3  (N quarter)
    const int lr   = lane & 15;
    const int lq   = lane >> 4;

    // per-thread A base: global row = t0*32 + row0 + wm*128 (+ m*16 + lr)
    const int rblk0 = ((t0 << 5) + row0) >> 4;
    const unsigned short* pA =
        x3 + (size_t)(rblk0 + wm * 8) * 8192 + lq * 128 + lr * 8;
    // addr(m, x, kt) = pA + m*8192 + kt*1024 + x*512

    auto stageB = [&](unsigned short* Bb, int kt) {
        const int k0 = kt * BKT;
        #pragma unroll
        for (int a = 0; a < 4; ++a) {
            int cid = a * 512 + tid;          // 16B-chunk id, 0..2047
            int rt  = cid >> 3;
            int cp  = cid & 7;
            int cl  = cp ^ (rt & 7);
            gl2lds16(W2 + (size_t)(col0 + rt) * DIN + k0 + cl * 8, Bb + rt * 64 + cp * 8);
        }
    };

    f32x4 acc[8][4] = {};

    stageB(Bs[0], 0);
    stageB(Bs[1], 1);
    asm volatile("s_waitcnt vmcnt(4)" ::: "memory");   // B(0) landed
    __builtin_amdgcn_s_barrier();

    #pragma unroll
    for (int kt = 0; kt < NKT; ++kt) {
        const unsigned short* Bb = Bs[kt & 1];

        // issue all 16 A-frag loads for this K-tile (1KB coalesced each)
        s16x8 av[8][2];
        #pragma unroll
        for (int m = 0; m < 8; ++m)
            #pragma unroll
            for (int x = 0; x < 2; ++x)
                av[m][x] = *(const s16x8*)(pA + m * 8192 + kt * 1024 + x * 512);

        // read the 8 B-frags from LDS (fully consumes Bb)
        s16x8 bv[4][2];
        #pragma unroll
        for (int j = 0; j < 4; ++j) {
            int col = wn * 64 + j * 16 + lr;
            #pragma unroll
            for (int x = 0; x < 2; ++x) {
                int cp = (x * 4 + lq) ^ (col & 7);
                bv[j][x] = *(const s16x8*)(Bb + col * 64 + cp * 8);
            }
        }
        asm volatile("s_waitcnt lgkmcnt(0)" ::: "memory");
        __builtin_amdgcn_sched_barrier(0);
        __builtin_amdgcn_s_barrier();            // all waves done with Bb
        if (kt + 2 < NKT) stageB(Bs[kt & 1], kt + 2);

        // MFMA: compiler inserts precise vmcnt waits for av arrival
        #pragma unroll
        for (int m = 0; m < 8; ++m) {
            __builtin_amdgcn_s_setprio(1);
            #pragma unroll
            for (int j = 0; j < 4; ++j) {
                acc[m][j] = __builtin_amdgcn_mfma_f32_16x16x32_bf16(
                    bv[j][0], av[m][0], acc[m][j], 0, 0, 0);
                acc[m][j] = __builtin_amdgcn_mfma_f32_16x16x32_bf16(
                    bv[j][1], av[m][1], acc[m][j], 0, 0, 0);
            }
            __builtin_amdgcn_s_setprio(0);
        }

        if (kt + 1 < NKT) {
            // all av consumed (completed); allow only stageB(kt+2) in flight
            if (kt + 2 < NKT)
                asm volatile("s_waitcnt vmcnt(4)" ::: "memory");
            else
                asm volatile("s_waitcnt vmcnt(0)" ::: "memory");
            __builtin_amdgcn_s_barrier();        // B(kt+1) ready for all
        }
    }

    // ---- epilogue: bias + gate activation + packed 8B stores ----
    const int p = col0 >> 10;                 // plane uniform per block
    const bool evenTanh = (p == 1);           // gate 2p: tanh iff k==2
    const bool oddIdent = (p == 2);           // gate 2p+1: identity iff k==5
    const float mEven = evenTanh ? 2.885390082f : -1.442695041f;

    #pragma unroll
    for (int m = 0; m < 8; ++m) {
        int prow = row0 + wm * 128 + m * 16 + lr;
        _Float16* dst = proj + (size_t)prow * PW;
        #pragma unroll
        for (int j = 0; j < 4; ++j) {
            int cbase = col0 + wn * 64 + j * 16 + lq * 4;
            float4 bc = *(const float4*)(bias2 + cbase);
            float z0 = acc[m][j][0] + bc.x;
            float z1 = acc[m][j][1] + bc.y;
            float z2 = acc[m][j][2] + bc.z;
            float z3 = acc[m][j][3] + bc.w;
            float e0 = __builtin_amdgcn_rcpf(1.f + __builtin_amdgcn_exp2f(z0 * mEven));
            float e2 = __builtin_amdgcn_rcpf(1.f + __builtin_amdgcn_exp2f(z2 * mEven));
            float v0 = evenTanh ? (1.f - 2.f * e0) : e0;
            float v2 = evenTanh ? (1.f - 2.f * e2) : e2;
            float v1 = oddIdent ? z1
                : __builtin_amdgcn_rcpf(1.f + __builtin_amdgcn_exp2f(z1 * -1.442695041f));
            float v3 = oddIdent ? z3
                : __builtin_amdgcn_rcpf(1.f + __builtin_amdgcn_exp2f(z3 * -1.442695041f));
            ushort4 o;
            o.x = __builtin_bit_cast(unsigned short, (_Float16)v0);
            o.y = __builtin_bit_cast(unsigned short, (_Float16)v1);
            o.z = __builtin_bit_cast(unsigned short, (_Float16)v2);
            o.w = __builtin_bit_cast(unsigned short, (_Float16)v3);
            *(ushort4*)(dst + cbase) = o;
        }
    }
}

// ---------------------------------------------------------------------------
// Scan: one thread per (b,d). 3 coalesced dword loads/step (pair planes):
//   plane0: (sig z0, sig z1)  plane1: (tanh z2, sig z3)  plane2: (sig z4, z5)
// PF=16 register prefetch.  s = a0*s + a1*t2 ; h = a3*h + a4*tanh(z5 + s)
// ---------------------------------------------------------------------------
__global__ __launch_bounds__(64) void scan_chunk(
    const _Float16* __restrict__ proj,   // [Tc*32][PW]
    const float* __restrict__ h0, const float* __restrict__ s0,
    float* __restrict__ outH, float* __restrict__ outS,
    int t0, int Tc)
{
    const int gid = blockIdx.x * 64 + threadIdx.x;   // 0..16383
    const int b   = gid >> 9;
    const int d   = gid & 511;

    float h, s;
    if (t0 == 0) { h = h0[gid]; s = s0[gid]; }
    else {
        h = outH[((size_t)b * TT + (t0 - 1)) * DD + d];
        s = outS[gid];
    }

    const unsigned* pu = (const unsigned*)(proj + (size_t)b * PW + d * 2);
    const size_t tstr = (size_t)BB * PW / 2;   // uints per step
    float* oH = outH + ((size_t)b * TT + t0) * DD + d;

    unsigned bufA[PF][3], bufB[PF][3];
    #pragma unroll
    for (int u = 0; u < PF; ++u)
        #pragma unroll
        for (int p = 0; p < 3; ++p)
            bufA[u][p] = pu[(size_t)u * tstr + p * 512];

    for (int tb = 0; tb < Tc; tb += 2 * PF) {
        #pragma unroll
        for (int u = 0; u < PF; ++u) {
            int t = tb + PF + u; if (t > Tc - 1) t = Tc - 1;
            #pragma unroll
            for (int p = 0; p < 3; ++p)
                bufB[u][p] = pu[(size_t)t * tstr + p * 512];
        }
        #pragma unroll
        for (int u = 0; u < PF; ++u) {
            float a0 = h2lo(bufA[u][0]), a1 = h2hi(bufA[u][0]);
            float t2 = h2lo(bufA[u][1]), a3 = h2hi(bufA[u][1]);
            float a4 = h2lo(bufA[u][2]), z5 = h2hi(bufA[u][2]);
            s = __builtin_fmaf(a0, s, a1 * t2);
            h = __builtin_fmaf(a3, h, a4 * ftanh(z5 + s));
            oH[(size_t)(tb + u) * DD] = h;
        }
        #pragma unroll
        for (int u = 0; u < PF; ++u) {
            int t = tb + 2 * PF + u; if (t > Tc - 1) t = Tc - 1;
            #pragma unroll
            for (int p = 0; p < 3; ++p)
                bufA[u][p] = pu[(size_t)t * tstr + p * 512];
        }
        #pragma unroll
        for (int u = 0; u < PF; ++u) {
            float a0 = h2lo(bufB[u][0]), a1 = h2hi(bufB[u][0]);
            float t2 = h2lo(bufB[u][1]), a3 = h2hi(bufB[u][1]);
            float a4 = h2lo(bufB[u][2]), z5 = h2hi(bufB[u][2]);
            s = __builtin_fmaf(a0, s, a1 * t2);
            h = __builtin_fmaf(a3, h, a4 * ftanh(z5 + s));
            oH[(size_t)(tb + PF + u) * DD] = h;
        }
    }

    outS[gid] = s;
}

// ---------------------------------------------------------------------------
extern "C" void kernel_launch(void* const* d_in, const int* in_sizes, int n_in,
                              void* d_out, int out_size, void* d_ws, size_t ws_size,
                              hipStream_t stream) {
    const float* x    = (const float*)d_in[0];
    const float* h0   = (const float*)d_in[1];
    const float* s0   = (const float*)d_in[2];
    const float* W    = (const float*)d_in[3];
    const float* bias = (const float*)d_in[4];

    float* outH = (float*)d_out;
    float* outS = outH + (size_t)BB * TT * DD;

    char* ws = (char*)d_ws;
    const size_t x3_bytes = (size_t)BB * TT * DIN * 2;       // 64 MB
    const size_t w2_bytes = (size_t)NN * DIN * 2;            // 3 MB
    const size_t b2_bytes = (size_t)NN * 4;
    unsigned short* x3    = (unsigned short*)ws;
    unsigned short* W2    = (unsigned short*)(ws + x3_bytes);
    float*          bias2 = (float*)(ws + x3_bytes + w2_bytes);
    _Float16*       proj  = (_Float16*)(ws + x3_bytes + w2_bytes + b2_bytes);

    const size_t fixed = x3_bytes + w2_bytes + b2_bytes;
    const size_t per_t = (size_t)BB * PW * 2;                // 192 KB / step
    size_t avail = ws_size > fixed ? ws_size - fixed : 0;
    int TcMax = (int)(avail / per_t);
    if (TcMax > 512) TcMax = 512;   // keep proj chunk L3-resident
    TcMax &= ~31;                   // multiple of 32 (scan 2*PF, M tile 256)
    if (TcMax < 32) TcMax = 32;

    convert_x<<<2048, 256, 0, stream>>>(x, x3);
    convert_w<<<NN, 128, 0, stream>>>(W, bias, W2, bias2);

    for (int t0 = 0; t0 < TT; t0 += TcMax) {
        int Tc = TT - t0;
        if (Tc > TcMax) Tc = TcMax;
        int nblk = (NN / BNT) * (Tc * BB / BMT);
        gemm_proj9<<<nblk, 512, 0, stream>>>(x3, W2, bias2, proj, t0);
        scan_chunk<<<(BB * DD) / 64, 64, 0, stream>>>(proj, h0, s0, outH, outS, t0, Tc);
    }
}

// Round 9
// 487.762 us; speedup vs baseline: 1.3797x; 1.3797x over previous
//
#include <hip/hip_runtime.h>
#include <hip/hip_bf16.h>
#include <cstddef>
#include <cstdint>

#define BB   32
#define TT   2048
#define DIN  512
#define DD   512
#define NN   3072
#define PW   3072    // proj row width (f16): col = p*1024 + d*2 + q, gate k=2p+q
#define PF   16      // scan prefetch depth (steps)

#define BMT 256      // GEMM tile M
#define BNT 256      // GEMM tile N
#define BKT 32       // GEMM K-tile
#define NKT (DIN / BKT)   // 16 K-tiles

typedef __attribute__((ext_vector_type(4))) float f32x4;
typedef __attribute__((ext_vector_type(8))) short s16x8;

// ---------------------------------------------------------------------------
// helpers
// ---------------------------------------------------------------------------
__device__ __forceinline__ void gl2lds16(const void* g, void* l) {
    __builtin_amdgcn_global_load_lds(
        (const __attribute__((address_space(1))) unsigned*)g,
        (__attribute__((address_space(3))) unsigned*)l, 16, 0, 0);
}

__device__ __forceinline__ unsigned short bfr(float f) {   // f32 -> bf16 RNE
    unsigned u = __float_as_uint(f);
    u += 0x7fffu + ((u >> 16) & 1u);
    return (unsigned short)(u >> 16);
}

__device__ __forceinline__ float ftanh(float x) {
    return 1.f - 2.f * __builtin_amdgcn_rcpf(1.f + __builtin_amdgcn_exp2f(x * 2.885390082f));
}

__device__ __forceinline__ float h2lo(unsigned u) {
    return (float)__builtin_bit_cast(_Float16, (unsigned short)(u & 0xffffu));
}
__device__ __forceinline__ float h2hi(unsigned u) {
    return (float)__builtin_bit_cast(_Float16, (unsigned short)(u >> 16));
}

// ---------------------------------------------------------------------------
// convert x [B][T][DIN] f32 -> x2 [(t*32+b)][DIN] bf16
// ---------------------------------------------------------------------------
__global__ __launch_bounds__(256) void convert_x(
    const float* __restrict__ x, unsigned short* __restrict__ x2)
{
    const int total4 = BB * TT * DIN / 4;
    for (int idx = blockIdx.x * 256 + threadIdx.x; idx < total4;
         idx += gridDim.x * 256) {
        int e = idx * 4;
        int b = e >> 20;
        int t = (e >> 9) & 2047;
        int i = e & 511;
        float4 v = *(const float4*)(x + (size_t)e);
        ushort4 o;
        o.x = bfr(v.x); o.y = bfr(v.y); o.z = bfr(v.z); o.w = bfr(v.w);
        *(ushort4*)(x2 + ((size_t)((t << 5) | b) << 9) + i) = o;
    }
}

// ---------------------------------------------------------------------------
// convert W: W2 row c (pair-planar): p = c>>10, d = (c&1023)>>1, q = c&1,
// gate k = 2p+q, original W row o = k*512 + d. bias permuted likewise.
// ---------------------------------------------------------------------------
__global__ __launch_bounds__(128) void convert_w(
    const float* __restrict__ W, const float* __restrict__ bias,
    unsigned short* __restrict__ W2, float* __restrict__ bias2)
{
    int c = blockIdx.x;            // 0..3071
    int p = c >> 10, d = (c & 1023) >> 1, q = c & 1;
    int o = ((2 * p + q) << 9) + d;
    const float* src = W + (size_t)o * DIN;
    unsigned short* dst = W2 + (size_t)c * DIN;
    int i = threadIdx.x * 4;
    float4 v = *(const float4*)(src + i);
    ushort4 u;
    u.x = bfr(v.x); u.y = bfr(v.y); u.z = bfr(v.z); u.w = bfr(v.w);
    *(ushort4*)(dst + i) = u;
    if (threadIdx.x == 0) bias2[c] = bias[o];
}

// ---------------------------------------------------------------------------
// 256x256 8-wave MFMA GEMM, BK=32, TRIPLE-buffered LDS (96 KB):
//   staging of K-tile kt+2 issued at the TOP of kt (2-tile lead),
//   boundary = counted vmcnt(4) + ONE barrier per K-tile (never drain to 0
//   until the tail). ds_read->MFMA hazards handled by compiler lgkmcnt.
// Read economy: 12 ds_read_b128 / wave / K-tile (8 av + 4 bv, no redundancy).
// 64B LDS row stride self-distributes banks (b128 floor, no swizzle needed).
// Operands swapped (A-op = W2 frag) -> packed 8B ushort4 epilogue stores.
// ---------------------------------------------------------------------------
__global__ __launch_bounds__(512, 2) void gemm_proj10(
    const unsigned short* __restrict__ x2,    // [T*32][512] bf16
    const unsigned short* __restrict__ W2,    // [3072][512] bf16 (permuted)
    const float* __restrict__ bias2,          // [3072] (permuted)
    _Float16* __restrict__ proj,              // [Mc][PW]
    int t0)
{
    // slot s: A tile (256x32) at lds + s*16384, B tile at +8192 (shorts)
    __shared__ unsigned short lds[3 * 16384];   // 96 KB

    // XCD-bijective swizzle (m204): contiguous work per XCD
    const unsigned nwg = gridDim.x;
    const unsigned fb  = blockIdx.x;
    const unsigned qq  = nwg >> 3, rr8 = nwg & 7;
    const unsigned xcd = fb & 7, sid = fb >> 3;
    const unsigned work = (xcd < rr8 ? xcd * (qq + 1)
                                     : rr8 * (qq + 1) + (xcd - rr8) * qq) + sid;
    const int bx = (int)(work % (NN / BNT));    // 12 col tiles
    const int by = (int)(work / (NN / BNT));

    const int tid  = threadIdx.x;
    const int row0 = by * BMT;                  // chunk-local
    const int col0 = bx * BNT;
    const size_t growA = (size_t)t0 * BB + row0;

    const int lane = tid & 63;
    const int wv   = tid >> 6;       // 0..7
    const int wm   = wv >> 2;        // 0..1  (M half)
    const int wn   = wv & 3;         // 0..3  (N quarter)
    const int lr   = lane & 15;
    const int lq   = lane >> 4;

    // stage one K-tile (A: 2 loads/thread, B: 2 loads/thread, 16B each)
    auto stageA = [&](int s, int kt) {
        unsigned short* Ab = lds + s * 16384;
        const int k0 = kt * BKT;
        #pragma unroll
        for (int a = 0; a < 2; ++a) {
            int cid = a * 512 + tid;        // 0..1023
            int rt  = cid >> 2;             // row
            int cp  = cid & 3;              // 16B chunk in row
            gl2lds16(x2 + (growA + rt) * DIN + k0 + cp * 8, Ab + cid * 8);
        }
    };
    auto stageB = [&](int s, int kt) {
        unsigned short* Bb = lds + s * 16384 + 8192;
        const int k0 = kt * BKT;
        #pragma unroll
        for (int a = 0; a < 2; ++a) {
            int cid = a * 512 + tid;
            int rt  = cid >> 2;
            int cp  = cid & 3;
            gl2lds16(W2 + (size_t)(col0 + rt) * DIN + k0 + cp * 8, Bb + cid * 8);
        }
    };

    f32x4 acc[8][4] = {};

    // prologue: K-tiles 0,1 in flight; wait tile 0 (tile 1 stays in flight)
    stageA(0, 0); stageB(0, 0);
    stageA(1, 1); stageB(1, 1);
    asm volatile("s_waitcnt vmcnt(4)" ::: "memory");
    __builtin_amdgcn_s_barrier();

    #pragma unroll
    for (int kt = 0; kt < NKT; ++kt) {
        const unsigned short* Ab = lds + (kt % 3) * 16384;
        const unsigned short* Bb = Ab + 8192;
        const int  ks = (kt + 2) % 3;
        const bool st = (kt + 2) < NKT;

        // issue next+1 staging FIRST: latency spans this whole K-tile
        if (st) { stageA(ks, kt + 2); stageB(ks, kt + 2); }

        // frag reads (compiler interleaves with MFMA via fine lgkmcnt)
        s16x8 bv[4], av[8];
        #pragma unroll
        for (int j = 0; j < 4; ++j) {
            int col = wn * 64 + j * 16 + lr;
            bv[j] = *(const s16x8*)(Bb + col * BKT + lq * 8);
        }
        #pragma unroll
        for (int m = 0; m < 8; ++m) {
            int row = wm * 128 + m * 16 + lr;
            av[m] = *(const s16x8*)(Ab + row * BKT + lq * 8);
        }

        __builtin_amdgcn_s_setprio(1);
        #pragma unroll
        for (int m = 0; m < 8; ++m)
            #pragma unroll
            for (int j = 0; j < 4; ++j)
                acc[m][j] = __builtin_amdgcn_mfma_f32_16x16x32_bf16(
                    bv[j], av[m], acc[m][j], 0, 0, 0);
        __builtin_amdgcn_s_setprio(0);

        // boundary: K-tile kt+1 (oldest 4 loads) must be landed for ALL waves
        if (kt + 1 < NKT) {
            if (st) asm volatile("s_waitcnt vmcnt(4)" ::: "memory");
            else    asm volatile("s_waitcnt vmcnt(0)" ::: "memory");
            __builtin_amdgcn_s_barrier();
        }
    }

    // ---- epilogue: bias + gate activation + packed 8B stores ----
    const int p = col0 >> 10;                 // plane uniform per block
    const bool evenTanh = (p == 1);           // gate 2p: tanh iff k==2
    const bool oddIdent = (p == 2);           // gate 2p+1: identity iff k==5
    const float mEven = evenTanh ? 2.885390082f : -1.442695041f;

    #pragma unroll
    for (int m = 0; m < 8; ++m) {
        int prow = row0 + wm * 128 + m * 16 + lr;
        _Float16* dst = proj + (size_t)prow * PW;
        #pragma unroll
        for (int j = 0; j < 4; ++j) {
            int cbase = col0 + wn * 64 + j * 16 + lq * 4;
            float4 bc = *(const float4*)(bias2 + cbase);
            float z0 = acc[m][j][0] + bc.x;
            float z1 = acc[m][j][1] + bc.y;
            float z2 = acc[m][j][2] + bc.z;
            float z3 = acc[m][j][3] + bc.w;
            float e0 = __builtin_amdgcn_rcpf(1.f + __builtin_amdgcn_exp2f(z0 * mEven));
            float e2 = __builtin_amdgcn_rcpf(1.f + __builtin_amdgcn_exp2f(z2 * mEven));
            float v0 = evenTanh ? (1.f - 2.f * e0) : e0;
            float v2 = evenTanh ? (1.f - 2.f * e2) : e2;
            float v1 = oddIdent ? z1
                : __builtin_amdgcn_rcpf(1.f + __builtin_amdgcn_exp2f(z1 * -1.442695041f));
            float v3 = oddIdent ? z3
                : __builtin_amdgcn_rcpf(1.f + __builtin_amdgcn_exp2f(z3 * -1.442695041f));
            ushort4 o;
            o.x = __builtin_bit_cast(unsigned short, (_Float16)v0);
            o.y = __builtin_bit_cast(unsigned short, (_Float16)v1);
            o.z = __builtin_bit_cast(unsigned short, (_Float16)v2);
            o.w = __builtin_bit_cast(unsigned short, (_Float16)v3);
            *(ushort4*)(dst + cbase) = o;
        }
    }
}

// ---------------------------------------------------------------------------
// Scan: one thread per (b,d). 3 coalesced dword loads/step (pair planes):
//   plane0: (sig z0, sig z1)  plane1: (tanh z2, sig z3)  plane2: (sig z4, z5)
// PF=16 register prefetch.  s = a0*s + a1*t2 ; h = a3*h + a4*tanh(z5 + s)
// ---------------------------------------------------------------------------
__global__ __launch_bounds__(64) void scan_chunk(
    const _Float16* __restrict__ proj,   // [Tc*32][PW]
    const float* __restrict__ h0, const float* __restrict__ s0,
    float* __restrict__ outH, float* __restrict__ outS,
    int t0, int Tc)
{
    const int gid = blockIdx.x * 64 + threadIdx.x;   // 0..16383
    const int b   = gid >> 9;
    const int d   = gid & 511;

    float h, s;
    if (t0 == 0) { h = h0[gid]; s = s0[gid]; }
    else {
        h = outH[((size_t)b * TT + (t0 - 1)) * DD + d];
        s = outS[gid];
    }

    const unsigned* pu = (const unsigned*)(proj + (size_t)b * PW + d * 2);
    const size_t tstr = (size_t)BB * PW / 2;   // uints per step
    float* oH = outH + ((size_t)b * TT + t0) * DD + d;

    unsigned bufA[PF][3], bufB[PF][3];
    #pragma unroll
    for (int u = 0; u < PF; ++u)
        #pragma unroll
        for (int p = 0; p < 3; ++p)
            bufA[u][p] = pu[(size_t)u * tstr + p * 512];

    for (int tb = 0; tb < Tc; tb += 2 * PF) {
        #pragma unroll
        for (int u = 0; u < PF; ++u) {
            int t = tb + PF + u; if (t > Tc - 1) t = Tc - 1;
            #pragma unroll
            for (int p = 0; p < 3; ++p)
                bufB[u][p] = pu[(size_t)t * tstr + p * 512];
        }
        #pragma unroll
        for (int u = 0; u < PF; ++u) {
            float a0 = h2lo(bufA[u][0]), a1 = h2hi(bufA[u][0]);
            float t2 = h2lo(bufA[u][1]), a3 = h2hi(bufA[u][1]);
            float a4 = h2lo(bufA[u][2]), z5 = h2hi(bufA[u][2]);
            s = __builtin_fmaf(a0, s, a1 * t2);
            h = __builtin_fmaf(a3, h, a4 * ftanh(z5 + s));
            oH[(size_t)(tb + u) * DD] = h;
        }
        #pragma unroll
        for (int u = 0; u < PF; ++u) {
            int t = tb + 2 * PF + u; if (t > Tc - 1) t = Tc - 1;
            #pragma unroll
            for (int p = 0; p < 3; ++p)
                bufA[u][p] = pu[(size_t)t * tstr + p * 512];
        }
        #pragma unroll
        for (int u = 0; u < PF; ++u) {
            float a0 = h2lo(bufB[u][0]), a1 = h2hi(bufB[u][0]);
            float t2 = h2lo(bufB[u][1]), a3 = h2hi(bufB[u][1]);
            float a4 = h2lo(bufB[u][2]), z5 = h2hi(bufB[u][2]);
            s = __builtin_fmaf(a0, s, a1 * t2);
            h = __builtin_fmaf(a3, h, a4 * ftanh(z5 + s));
            oH[(size_t)(tb + PF + u) * DD] = h;
        }
    }

    outS[gid] = s;
}

// ---------------------------------------------------------------------------
extern "C" void kernel_launch(void* const* d_in, const int* in_sizes, int n_in,
                              void* d_out, int out_size, void* d_ws, size_t ws_size,
                              hipStream_t stream) {
    const float* x    = (const float*)d_in[0];
    const float* h0   = (const float*)d_in[1];
    const float* s0   = (const float*)d_in[2];
    const float* W    = (const float*)d_in[3];
    const float* bias = (const float*)d_in[4];

    float* outH = (float*)d_out;
    float* outS = outH + (size_t)BB * TT * DD;

    char* ws = (char*)d_ws;
    const size_t x2_bytes = (size_t)BB * TT * DIN * 2;       // 64 MB
    const size_t w2_bytes = (size_t)NN * DIN * 2;            // 3 MB
    const size_t b2_bytes = (size_t)NN * 4;
    unsigned short* x2    = (unsigned short*)ws;
    unsigned short* W2    = (unsigned short*)(ws + x2_bytes);
    float*          bias2 = (float*)(ws + x2_bytes + w2_bytes);
    _Float16*       proj  = (_Float16*)(ws + x2_bytes + w2_bytes + b2_bytes);

    const size_t fixed = x2_bytes + w2_bytes + b2_bytes;
    const size_t per_t = (size_t)BB * PW * 2;                // 192 KB / step
    size_t avail = ws_size > fixed ? ws_size - fixed : 0;
    int TcMax = (int)(avail / per_t);
    if (TcMax > 512) TcMax = 512;   // keep proj chunk L3-resident
    TcMax &= ~31;                   // multiple of 32 (scan 2*PF, M tile 256)
    if (TcMax < 32) TcMax = 32;

    convert_x<<<2048, 256, 0, stream>>>(x, x2);
    convert_w<<<NN, 128, 0, stream>>>(W, bias, W2, bias2);

    for (int t0 = 0; t0 < TT; t0 += TcMax) {
        int Tc = TT - t0;
        if (Tc > TcMax) Tc = TcMax;
        int nblk = (NN / BNT) * (Tc * BB / BMT);
        gemm_proj10<<<nblk, 512, 0, stream>>>(x2, W2, bias2, proj, t0);
        scan_chunk<<<(BB * DD) / 64, 64, 0, stream>>>(proj, h0, s0, outH, outS, t0, Tc);
    }
}